// Round 1
// baseline (182.311 us; speedup 1.0000x reference)
//
#include <hip/hip_runtime.h>

// IAF chain encoder, fully fused: one block = 32 batch rows, runs all 4 flow
// steps in-LDS. Weights pre-masked + transposed + fp16-cast into d_ws by a
// prep kernel. GEMMs via mfma_f32_16x16x32_f16, fp32 accum.
//
// B=8192, D=256, H=512, T=4. Output fp32 (B,D).

typedef _Float16 f16;
typedef __attribute__((ext_vector_type(8))) _Float16 f16x8;
typedef __attribute__((ext_vector_type(4))) float f32x4;

#define NB 8192
#define ND 256
#define NH 512
#define NT 4

// ws layout (fp16 elements):
#define W1T_OFF 0                        // [T][NH][ND]  (W1^T masked)
#define W2T_OFF (NT*NH*ND)               // [T][NH][NH]  (W2^T masked)
#define W3T_OFF (W2T_OFF + NT*NH*NH)     // [T][NH][NH]  (W3^T masked)
#define WS_ELEMS (W3T_OFF + NT*NH*NH)    // 2,621,440 els = 5.24 MB

// deg_in[k] = k+1 (k in 0..255); deg_h[n] = 1 + n%255 (n in 0..511)
// M1[k][n] = deg_h[n] >= deg_in[k]  ->  (1 + n%255) >= k+1
// M2[k][n] = deg_h[n] >= deg_h[k]   ->  (n%255) >= (k%255)
// M3[k][n] = deg_in[n>>1] > deg_h[k] -> (n>>1) > (k%255)
__global__ void prep_weights(const float* __restrict__ W1,
                             const float* __restrict__ W2,
                             const float* __restrict__ W3,
                             f16* __restrict__ ws)
{
  int idx = blockIdx.x * blockDim.x + threadIdx.x;
  if (idx >= WS_ELEMS) return;
  float v;
  if (idx < W2T_OFF) {
    int t = idx >> 17, r = idx & ((1 << 17) - 1);   // NH*ND = 131072
    int n = r >> 8, k = r & 255;
    v = ((1 + n % 255) >= (k + 1)) ? W1[t * (ND * NH) + k * NH + n] : 0.f;
  } else if (idx < W3T_OFF) {
    int j = idx - W2T_OFF;
    int t = j >> 18, r = j & ((1 << 18) - 1);       // NH*NH = 262144
    int n = r >> 9, k = r & 511;
    v = ((n % 255) >= (k % 255)) ? W2[t * (NH * NH) + k * NH + n] : 0.f;
  } else {
    int j = idx - W3T_OFF;
    int t = j >> 18, r = j & ((1 << 18) - 1);
    int n = r >> 9, k = r & 511;
    v = ((n >> 1) > (k % 255)) ? W3[t * (NH * 2 * ND) + k * (2 * ND) + n] : 0.f;
  }
  ws[idx] = (f16)v;
}

// One wave owns a 64-column N-panel, both 16-row M-tiles (M=32 per block).
// srcA: LDS fp16, row-major, row stride SSTRB bytes, XOR-swizzled by
// byte ^= (row&7)<<4.  Wt: global [512][K] fp16 (transposed, masked).
template<int K, int SSTRB>
__device__ __forceinline__ void gemm_block(const f16* srcA,
                                           const f16* __restrict__ Wt,
                                           int lrow, int lk8, int npanel,
                                           f32x4 (&acc)[2][4])
{
  #pragma unroll
  for (int mt = 0; mt < 2; ++mt)
    #pragma unroll
    for (int nt = 0; nt < 4; ++nt)
      acc[mt][nt] = (f32x4){0.f, 0.f, 0.f, 0.f};

  #pragma unroll 4
  for (int ks = 0; ks < K / 32; ++ks) {
    f16x8 a[2], b[4];
    #pragma unroll
    for (int mt = 0; mt < 2; ++mt) {
      int row = mt * 16 + lrow;
      int off = row * SSTRB + (ks * 32 + lk8 * 8) * 2;
      a[mt] = *(const f16x8*)((const char*)srcA + (off ^ ((row & 7) << 4)));
    }
    #pragma unroll
    for (int nt = 0; nt < 4; ++nt) {
      int n = npanel + nt * 16 + lrow;
      b[nt] = *(const f16x8*)(Wt + n * K + ks * 32 + lk8 * 8);
    }
    #pragma unroll
    for (int mt = 0; mt < 2; ++mt)
      #pragma unroll
      for (int nt = 0; nt < 4; ++nt)
        acc[mt][nt] = __builtin_amdgcn_mfma_f32_16x16x32_f16(a[mt], b[nt],
                                                             acc[mt][nt], 0, 0, 0);
  }
}

// relu(acc + bias) -> fp16 LDS tile [32][512], swizzled, row stride 1024B
__device__ __forceinline__ void epi_relu(const f32x4 (&acc)[2][4],
                                         const float* __restrict__ bias,
                                         f16* dst, int lrow, int lk8, int npanel)
{
  #pragma unroll
  for (int nt = 0; nt < 4; ++nt) {
    int n = npanel + nt * 16 + lrow;
    float bv = bias[n];
    #pragma unroll
    for (int mt = 0; mt < 2; ++mt)
      #pragma unroll
      for (int j = 0; j < 4; ++j) {
        int m = mt * 16 + lk8 * 4 + j;                 // C/D: row=(lane>>4)*4+j
        float v = fmaxf(acc[mt][nt][j] + bv, 0.f);
        int off = m * 1024 + n * 2;
        *(f16*)((char*)dst + (off ^ ((m & 7) << 4))) = (f16)v;
      }
  }
}

__global__ __launch_bounds__(512, 2) void iaf_main(
    const float* __restrict__ mean, const float* __restrict__ logv,
    const float* __restrict__ eps,
    const float* __restrict__ b1, const float* __restrict__ b2,
    const float* __restrict__ b3,
    const f16* __restrict__ ws, float* __restrict__ out)
{
  __shared__ float xbuf[32][256];                 // 32 KB, fp32 master copy of x
  __shared__ __align__(16) f16 buf0[32 * 512];    // 32 KB  (A1 uses 16 KB of it)
  __shared__ __align__(16) f16 buf1[32 * 512];    // 32 KB

  const int tid = threadIdx.x;
  const int wid = tid >> 6;
  const int lane = tid & 63;
  const int lrow = lane & 15;    // MFMA row (A) / col (B,C)
  const int lk8 = lane >> 4;     // MFMA k-chunk / row-group
  const int npanel = wid * 64;   // this wave's 64-column output panel
  const int row0 = blockIdx.x * 32;

  // x0 = mean + exp(0.5*log_var)*eps   (coalesced float4 loads)
  {
    int m = tid >> 4;
    int c0 = (tid & 15) * 16;
    const int g = (row0 + m) * ND + c0;
    #pragma unroll
    for (int i = 0; i < 16; i += 4) {
      f32x4 mu = *(const f32x4*)(mean + g + i);
      f32x4 lv = *(const f32x4*)(logv + g + i);
      f32x4 ep = *(const f32x4*)(eps + g + i);
      f32x4 x;
      #pragma unroll
      for (int q = 0; q < 4; ++q) x[q] = mu[q] + __expf(0.5f * lv[q]) * ep[q];
      *(f32x4*)(&xbuf[m][c0 + i]) = x;
    }
  }
  __syncthreads();

  for (int t = NT - 1; t >= 0; --t) {
    // A1[m][k] = fp16(x[m][255-k])  (reversal folded in), stride 512B, swizzled
    {
      int m = tid >> 4;
      #pragma unroll
      for (int half = 0; half < 2; ++half) {
        int k0 = (tid & 15) * 8 + half * 128;
        f32x4 lo = *(const f32x4*)(&xbuf[m][248 - k0]);
        f32x4 hi = *(const f32x4*)(&xbuf[m][252 - k0]);
        f16x8 pk;
        pk[0] = (f16)hi[3]; pk[1] = (f16)hi[2]; pk[2] = (f16)hi[1]; pk[3] = (f16)hi[0];
        pk[4] = (f16)lo[3]; pk[5] = (f16)lo[2]; pk[6] = (f16)lo[1]; pk[7] = (f16)lo[0];
        int off = m * 512 + k0 * 2;
        *(f16x8*)((char*)buf0 + (off ^ ((m & 7) << 4))) = pk;
      }
    }
    __syncthreads();

    f32x4 acc[2][4];

    // h1 = relu(x_rev @ W1m + b1)
    gemm_block<ND, 512>(buf0, ws + W1T_OFF + t * (NH * ND), lrow, lk8, npanel, acc);
    epi_relu(acc, b1 + t * NH, buf1, lrow, lk8, npanel);
    __syncthreads();

    // h2 = relu(h1 @ W2m + b2)
    gemm_block<NH, 1024>(buf1, ws + W2T_OFF + t * (NH * NH), lrow, lk8, npanel, acc);
    epi_relu(acc, b2 + t * NH, buf0, lrow, lk8, npanel);
    __syncthreads();

    // out = h2 @ W3m + b3 ;  shift = out[:,2d], lv = out[:,2d+1]
    gemm_block<NH, 1024>(buf0, ws + W3T_OFF + t * (NH * NH), lrow, lk8, npanel, acc);
    {
      float xn[2][4][4];
      const float* b3t = b3 + t * (2 * ND);
      #pragma unroll
      for (int nt = 0; nt < 4; ++nt) {
        int n = npanel + nt * 16 + lrow;
        float bv = b3t[n];
        #pragma unroll
        for (int mt = 0; mt < 2; ++mt)
          #pragma unroll
          for (int j = 0; j < 4; ++j) {
            float o = acc[mt][nt][j] + bv;     // my column's value (+its bias)
            float po = __shfl_xor(o, 1);       // partner column (n^1) value
            int m = mt * 16 + lk8 * 4 + j;
            int d = n >> 1;
            float xc = xbuf[m][255 - d];       // reversed x
            float e2 = __expf(2.f * po);       // tanh(po) = 1 - 2/(e^{2po}+1)
            float tl = 1.f - 2.f / (e2 + 1.f);
            xn[mt][nt][j] = (xc - o) * __expf(-tl);
          }
      }
      __syncthreads();                          // all xbuf reads done
      if ((lrow & 1) == 0) {                    // even columns hold shift -> d
        #pragma unroll
        for (int nt = 0; nt < 4; ++nt) {
          int d = (npanel + nt * 16 + lrow) >> 1;
          #pragma unroll
          for (int mt = 0; mt < 2; ++mt)
            #pragma unroll
            for (int j = 0; j < 4; ++j)
              xbuf[mt * 16 + lk8 * 4 + j][d] = xn[mt][nt][j];
        }
      }
      __syncthreads();
    }
  }

  // store final x (fp32)
  {
    int m = tid >> 4;
    int c0 = (tid & 15) * 16;
    float* op = out + (row0 + m) * ND + c0;
    #pragma unroll
    for (int i = 0; i < 16; i += 4)
      *(f32x4*)(op + i) = *(const f32x4*)(&xbuf[m][c0 + i]);
  }
}

extern "C" void kernel_launch(void* const* d_in, const int* in_sizes, int n_in,
                              void* d_out, int out_size, void* d_ws, size_t ws_size,
                              hipStream_t stream) {
  const float* mean = (const float*)d_in[0];
  const float* logv = (const float*)d_in[1];
  const float* eps  = (const float*)d_in[2];
  const float* W1   = (const float*)d_in[3];
  const float* b1   = (const float*)d_in[4];
  const float* W2   = (const float*)d_in[5];
  const float* b2   = (const float*)d_in[6];
  const float* W3   = (const float*)d_in[7];
  const float* b3   = (const float*)d_in[8];
  f16* ws = (f16*)d_ws;   // needs 5.25 MB

  prep_weights<<<(WS_ELEMS + 255) / 256, 256, 0, stream>>>(W1, W2, W3, ws);
  iaf_main<<<NB / 32, 512, 0, stream>>>(mean, logv, eps, b1, b2, b3, ws,
                                        (float*)d_out);
}

// Round 2
// 177.059 us; speedup vs baseline: 1.0297x; 1.0297x over previous
//
#include <hip/hip_runtime.h>

// IAF chain encoder, fully fused: one block = 32 batch rows, runs all 4 flow
// steps in-LDS. Weights pre-masked + transposed + fp16-cast into d_ws by a
// prep kernel. GEMMs via mfma_f32_16x16x32_f16, fp32 accum.
// Round 2: 16 waves/block (4/SIMD), double-buffered B prefetch, packed
// b32 epilogue stores.

typedef _Float16 f16;
typedef __attribute__((ext_vector_type(8))) _Float16 f16x8;
typedef __attribute__((ext_vector_type(4))) float f32x4;

#define NB 8192
#define ND 256
#define NH 512
#define NT 4
#define XSTR 260   // xbuf row stride (floats): 16B-aligned rows, 2-way banks

// ws layout (fp16 elements):
#define W1T_OFF 0                        // [T][NH][ND]  (W1^T masked)
#define W2T_OFF (NT*NH*ND)               // [T][NH][NH]  (W2^T masked)
#define W3T_OFF (W2T_OFF + NT*NH*NH)     // [T][NH][NH]  (W3^T masked)
#define WS_ELEMS (W3T_OFF + NT*NH*NH)    // 2,621,440 els = 5.24 MB

// deg_in[k] = k+1 (k in 0..255); deg_h[n] = 1 + n%255 (n in 0..511)
__global__ void prep_weights(const float* __restrict__ W1,
                             const float* __restrict__ W2,
                             const float* __restrict__ W3,
                             f16* __restrict__ ws)
{
  int idx = blockIdx.x * blockDim.x + threadIdx.x;
  if (idx >= WS_ELEMS) return;
  float v;
  if (idx < W2T_OFF) {
    int t = idx >> 17, r = idx & ((1 << 17) - 1);   // NH*ND = 131072
    int n = r >> 8, k = r & 255;
    v = ((1 + n % 255) >= (k + 1)) ? W1[t * (ND * NH) + k * NH + n] : 0.f;
  } else if (idx < W3T_OFF) {
    int j = idx - W2T_OFF;
    int t = j >> 18, r = j & ((1 << 18) - 1);       // NH*NH = 262144
    int n = r >> 9, k = r & 511;
    v = ((n % 255) >= (k % 255)) ? W2[t * (NH * NH) + k * NH + n] : 0.f;
  } else {
    int j = idx - W3T_OFF;
    int t = j >> 18, r = j & ((1 << 18) - 1);
    int n = r >> 9, k = r & 511;
    v = ((n >> 1) > (k % 255)) ? W3[t * (NH * 2 * ND) + k * (2 * ND) + n] : 0.f;
  }
  ws[idx] = (f16)v;
}

// One wave owns a 32-column N-panel (nt=2), both 16-row M-tiles (M=32/block).
// srcA: LDS fp16, row-major, row stride SSTRB bytes, swizzled byte^=(row&7)<<4.
// Wt: global [512][K] fp16 (transposed, masked).
// Double-buffered B prefetch at 2-ks (64-k) granularity, fully unrolled so all
// buffer indices are compile-time (rule: runtime-indexed vectors -> scratch).
template<int K, int SSTRB>
__device__ __forceinline__ void gemm_block(const f16* srcA,
                                           const f16* __restrict__ Wt,
                                           int lrow, int lk8, int npanel,
                                           f32x4 (&acc)[2][2])
{
  constexpr int NKS = K / 32;      // 8 or 16
  constexpr int NC = NKS / 2;      // chunks of 2 ks

  #pragma unroll
  for (int mt = 0; mt < 2; ++mt)
    #pragma unroll
    for (int nt = 0; nt < 2; ++nt)
      acc[mt][nt] = (f32x4){0.f, 0.f, 0.f, 0.f};

  const f16* w0 = Wt + (npanel + lrow) * K + lk8 * 8;        // nt=0 column
  const f16* w1 = w0 + 16 * K;                               // nt=1 column

  f16x8 b[2][2][2];   // [buf][ksub][nt]
  #pragma unroll
  for (int u = 0; u < 2; ++u) {
    b[0][u][0] = *(const f16x8*)(w0 + u * 32);
    b[0][u][1] = *(const f16x8*)(w1 + u * 32);
  }

  #pragma unroll
  for (int c = 0; c < NC; ++c) {
    const int cur = c & 1, nxt = cur ^ 1;
    if (c + 1 < NC) {
      #pragma unroll
      for (int u = 0; u < 2; ++u) {
        b[nxt][u][0] = *(const f16x8*)(w0 + (c * 2 + 2 + u) * 32);
        b[nxt][u][1] = *(const f16x8*)(w1 + (c * 2 + 2 + u) * 32);
      }
    }
    #pragma unroll
    for (int u = 0; u < 2; ++u) {
      const int ks = c * 2 + u;
      f16x8 a[2];
      #pragma unroll
      for (int mt = 0; mt < 2; ++mt) {
        int row = mt * 16 + lrow;
        int off = row * SSTRB + (ks * 32 + lk8 * 8) * 2;
        a[mt] = *(const f16x8*)((const char*)srcA + (off ^ ((row & 7) << 4)));
      }
      #pragma unroll
      for (int mt = 0; mt < 2; ++mt)
        #pragma unroll
        for (int nt = 0; nt < 2; ++nt)
          acc[mt][nt] = __builtin_amdgcn_mfma_f32_16x16x32_f16(a[mt], b[cur][u][nt],
                                                               acc[mt][nt], 0, 0, 0);
    }
  }
}

// relu(acc + bias) -> fp16 LDS tile [32][512], swizzled, row stride 1024B.
// Packed pair-stores: even lanes write the mt=0 row's (n,n+1) pair, odd lanes
// the mt=1 row's pair -> all-lane ds_write_b32, no same-dword conflicts.
__device__ __forceinline__ void epi_relu(const f32x4 (&acc)[2][2],
                                         const float* __restrict__ bias,
                                         f16* dst, int lrow, int lk8, int npanel)
{
  const bool ev = (lrow & 1) == 0;
  #pragma unroll
  for (int nt = 0; nt < 2; ++nt) {
    int n = npanel + nt * 16 + lrow;
    float bv = bias[n];
    #pragma unroll
    for (int j = 0; j < 4; ++j) {
      float v0 = fmaxf(acc[0][nt][j] + bv, 0.f);
      float v1 = fmaxf(acc[1][nt][j] + bv, 0.f);
      float p0 = __shfl_xor(v0, 1);
      float p1 = __shfl_xor(v1, 1);
      float lo = ev ? v0 : p1;
      float hi = ev ? p0 : v1;
      int m = (ev ? 0 : 16) + lk8 * 4 + j;
      int nw = n & ~1;
      unsigned int w = (unsigned int)__builtin_bit_cast(unsigned short, (f16)lo)
                     | ((unsigned int)__builtin_bit_cast(unsigned short, (f16)hi) << 16);
      int off = m * 1024 + nw * 2;
      *(unsigned int*)((char*)dst + (off ^ ((m & 7) << 4))) = w;
    }
  }
}

__global__ __launch_bounds__(1024, 4) void iaf_main(
    const float* __restrict__ mean, const float* __restrict__ logv,
    const float* __restrict__ eps,
    const float* __restrict__ b1, const float* __restrict__ b2,
    const float* __restrict__ b3,
    const f16* __restrict__ ws, float* __restrict__ out)
{
  __shared__ float xbuf[32][XSTR];                // 33.3 KB fp32 master x
  __shared__ __align__(16) f16 buf0[32 * 512];    // 32 KB (A1 uses 16 KB)
  __shared__ __align__(16) f16 buf1[32 * 512];    // 32 KB

  const int tid = threadIdx.x;
  const int wid = tid >> 6;
  const int lane = tid & 63;
  const int lrow = lane & 15;    // MFMA row (A) / col (B,C)
  const int lk8 = lane >> 4;     // MFMA k-chunk / row-group
  const int npanel = wid * 32;   // this wave's 32-column output panel
  const int row0 = blockIdx.x * 32;

  // x0 = mean + exp(0.5*log_var)*eps   (8 floats per thread, coalesced)
  {
    int m = tid >> 5;
    int c0 = (tid & 31) * 8;
    const int g = (row0 + m) * ND + c0;
    #pragma unroll
    for (int i = 0; i < 8; i += 4) {
      f32x4 mu = *(const f32x4*)(mean + g + i);
      f32x4 lv = *(const f32x4*)(logv + g + i);
      f32x4 ep = *(const f32x4*)(eps + g + i);
      f32x4 x;
      #pragma unroll
      for (int q = 0; q < 4; ++q) x[q] = mu[q] + __expf(0.5f * lv[q]) * ep[q];
      *(f32x4*)(&xbuf[m][c0 + i]) = x;
    }
  }
  __syncthreads();

  for (int t = NT - 1; t >= 0; --t) {
    // A1[m][k] = fp16(x[m][255-k]) (reversal folded in), stride 512B, swizzled
    {
      int m = tid >> 5;
      int k0 = (tid & 31) * 8;
      f32x4 lo = *(const f32x4*)(&xbuf[m][248 - k0]);
      f32x4 hi = *(const f32x4*)(&xbuf[m][252 - k0]);
      f16x8 pk;
      pk[0] = (f16)hi[3]; pk[1] = (f16)hi[2]; pk[2] = (f16)hi[1]; pk[3] = (f16)hi[0];
      pk[4] = (f16)lo[3]; pk[5] = (f16)lo[2]; pk[6] = (f16)lo[1]; pk[7] = (f16)lo[0];
      int off = m * 512 + k0 * 2;
      *(f16x8*)((char*)buf0 + (off ^ ((m & 7) << 4))) = pk;
    }
    __syncthreads();

    f32x4 acc[2][2];

    // h1 = relu(x_rev @ W1m + b1)
    gemm_block<ND, 512>(buf0, ws + W1T_OFF + t * (NH * ND), lrow, lk8, npanel, acc);
    epi_relu(acc, b1 + t * NH, buf1, lrow, lk8, npanel);
    __syncthreads();

    // h2 = relu(h1 @ W2m + b2)
    gemm_block<NH, 1024>(buf1, ws + W2T_OFF + t * (NH * NH), lrow, lk8, npanel, acc);
    epi_relu(acc, b2 + t * NH, buf0, lrow, lk8, npanel);
    __syncthreads();

    // out = h2 @ W3m + b3 ;  shift = out[:,2d], log_var = out[:,2d+1]
    gemm_block<NH, 1024>(buf0, ws + W3T_OFF + t * (NH * NH), lrow, lk8, npanel, acc);
    {
      const bool ev = (lrow & 1) == 0;
      float xn0[2][4], xn1[2][4];   // [nt][j] for m-rows (lk8*4+j) and (16+...)
      const float* b3t = b3 + t * (2 * ND);
      #pragma unroll
      for (int nt = 0; nt < 2; ++nt) {
        int n = npanel + nt * 16 + lrow;
        float bv = b3t[n];
        #pragma unroll
        for (int j = 0; j < 4; ++j) {
          float o0 = acc[0][nt][j] + bv;
          float o1 = acc[1][nt][j] + bv;
          float po0 = __shfl_xor(o0, 1);   // partner column (n^1) value
          float po1 = __shfl_xor(o1, 1);
          if (ev) {                         // even col: o=shift, po=pre-tanh lv
            int d = n >> 1;
            float xc = xbuf[lk8 * 4 + j][255 - d];
            float e0 = __expf(2.f * po0);
            float t0 = 1.f - 2.f / (e0 + 1.f);          // tanh(po0)
            xn0[nt][j] = (xc - o0) * __expf(-t0);
            float xc1 = xbuf[16 + lk8 * 4 + j][255 - d];
            float e1 = __expf(2.f * po1);
            float t1 = 1.f - 2.f / (e1 + 1.f);
            xn1[nt][j] = (xc1 - o1) * __expf(-t1);
          }
        }
      }
      __syncthreads();                      // all xbuf reads done
      if (ev) {
        #pragma unroll
        for (int nt = 0; nt < 2; ++nt) {
          int d = (npanel + nt * 16 + lrow) >> 1;
          #pragma unroll
          for (int j = 0; j < 4; ++j) {
            xbuf[lk8 * 4 + j][d]      = xn0[nt][j];
            xbuf[16 + lk8 * 4 + j][d] = xn1[nt][j];
          }
        }
      }
      __syncthreads();
    }
  }

  // store final x (fp32)
  {
    int m = tid >> 5;
    int c0 = (tid & 31) * 8;
    float* op = out + (row0 + m) * ND + c0;
    #pragma unroll
    for (int i = 0; i < 8; i += 4)
      *(f32x4*)(op + i) = *(const f32x4*)(&xbuf[m][c0 + i]);
  }
}

extern "C" void kernel_launch(void* const* d_in, const int* in_sizes, int n_in,
                              void* d_out, int out_size, void* d_ws, size_t ws_size,
                              hipStream_t stream) {
  const float* mean = (const float*)d_in[0];
  const float* logv = (const float*)d_in[1];
  const float* eps  = (const float*)d_in[2];
  const float* W1   = (const float*)d_in[3];
  const float* b1   = (const float*)d_in[4];
  const float* W2   = (const float*)d_in[5];
  const float* b2   = (const float*)d_in[6];
  const float* W3   = (const float*)d_in[7];
  const float* b3   = (const float*)d_in[8];
  f16* ws = (f16*)d_ws;   // needs 5.25 MB

  prep_weights<<<(WS_ELEMS + 255) / 256, 256, 0, stream>>>(W1, W2, W3, ws);
  iaf_main<<<NB / 32, 1024, 0, stream>>>(mean, logv, eps, b1, b2, b3, ws,
                                         (float*)d_out);
}

// Round 3
// 107.413 us; speedup vs baseline: 1.6973x; 1.6484x over previous
//
#include <hip/hip_runtime.h>

// IAF chain encoder, fully fused: one block = 32 batch rows, runs all 4 flow
// steps in-LDS. Weights pre-masked + fp16-cast into d_ws in MFMA-fragment-
// native order by a prep kernel. GEMMs via mfma_f32_16x16x32_f16, fp32 accum.
// Round 3: B-weights stored fragment-contiguous -> every B load is a fully
// coalesced 1KiB wave read (was: 16-line strided gather per load).

typedef _Float16 f16;
typedef __attribute__((ext_vector_type(8))) _Float16 f16x8;
typedef __attribute__((ext_vector_type(4))) float f32x4;

#define NB 8192
#define ND 256
#define NH 512
#define NT 4
#define XSTR 260   // xbuf row stride (floats)

// ws layout (fp16 elements), per gemm: [T][tile=NH/16][ks=K/32][lane=64][8]
#define W1F_OFF 0                        // [T][32][ 8][64][8]  = T*NH*ND
#define W2F_OFF (NT*NH*ND)               // [T][32][16][64][8]  = T*NH*NH
#define W3F_OFF (W2F_OFF + NT*NH*NH)     // [T][32][16][64][8]  = T*NH*NH
#define WS_ELEMS (W3F_OFF + NT*NH*NH)    // 2,621,440 els = 5.24 MB

// deg_in[k] = k+1 (k in 0..255); deg_h[n] = 1 + n%255 (n in 0..511)
// M1[k][n]: n%255 >= k ; M2[k][n]: n%255 >= k%255 ; M3[k][n]: n>>1 > k%255
__global__ void prep_weights(const float* __restrict__ W1,
                             const float* __restrict__ W2,
                             const float* __restrict__ W3,
                             f16* __restrict__ ws)
{
  int idx = blockIdx.x * blockDim.x + threadIdx.x;
  if (idx >= WS_ELEMS) return;
  float v;
  if (idx < W2F_OFF) {
    int t = idx >> 17, r = idx & ((1 << 17) - 1);     // NH*ND = 131072
    int e = r & 7, lane = (r >> 3) & 63, ks = (r >> 9) & 7, tile = r >> 12;
    int n = tile * 16 + (lane & 15);
    int k = ks * 32 + (lane >> 4) * 8 + e;
    v = ((n % 255) >= k) ? W1[t * (ND * NH) + k * NH + n] : 0.f;
  } else if (idx < W3F_OFF) {
    int j = idx - W2F_OFF;
    int t = j >> 18, r = j & ((1 << 18) - 1);         // NH*NH = 262144
    int e = r & 7, lane = (r >> 3) & 63, ks = (r >> 9) & 15, tile = r >> 13;
    int n = tile * 16 + (lane & 15);
    int k = ks * 32 + (lane >> 4) * 8 + e;
    v = ((n % 255) >= (k % 255)) ? W2[t * (NH * NH) + k * NH + n] : 0.f;
  } else {
    int j = idx - W3F_OFF;
    int t = j >> 18, r = j & ((1 << 18) - 1);
    int e = r & 7, lane = (r >> 3) & 63, ks = (r >> 9) & 15, tile = r >> 13;
    int n = tile * 16 + (lane & 15);
    int k = ks * 32 + (lane >> 4) * 8 + e;
    v = ((n >> 1) > (k % 255)) ? W3[t * (NH * 2 * ND) + k * (2 * ND) + n] : 0.f;
  }
  ws[idx] = (f16)v;
}

// One wave owns a 32-column N-panel (2 tiles), both 16-row M-tiles.
// srcA: LDS fp16, row-major, row stride SSTRB bytes, swizzled byte^=(row&7)<<4.
// Wt: global fragment-native [tile][K/32][64][8] fp16. Each B load is a
// contiguous 1KiB wave read. Double-buffered prefetch, fully unrolled.
template<int K, int SSTRB>
__device__ __forceinline__ void gemm_block(const f16* srcA,
                                           const f16* __restrict__ Wt,
                                           int lrow, int lk8, int lane, int tbase,
                                           f32x4 (&acc)[2][2])
{
  constexpr int NKS = K / 32;      // 8 or 16
  constexpr int NC = NKS / 2;      // chunks of 2 ks

  #pragma unroll
  for (int mt = 0; mt < 2; ++mt)
    #pragma unroll
    for (int nt = 0; nt < 2; ++nt)
      acc[mt][nt] = (f32x4){0.f, 0.f, 0.f, 0.f};

  const f16* w0 = Wt + ((tbase + 0) * NKS * 64 + lane) * 8;  // nt=0 tile
  const f16* w1 = Wt + ((tbase + 1) * NKS * 64 + lane) * 8;  // nt=1 tile

  f16x8 b[2][2][2];   // [buf][ksub][nt]
  #pragma unroll
  for (int u = 0; u < 2; ++u) {
    b[0][u][0] = *(const f16x8*)(w0 + u * 512);
    b[0][u][1] = *(const f16x8*)(w1 + u * 512);
  }

  #pragma unroll
  for (int c = 0; c < NC; ++c) {
    const int cur = c & 1, nxt = cur ^ 1;
    if (c + 1 < NC) {
      #pragma unroll
      for (int u = 0; u < 2; ++u) {
        b[nxt][u][0] = *(const f16x8*)(w0 + (c * 2 + 2 + u) * 512);
        b[nxt][u][1] = *(const f16x8*)(w1 + (c * 2 + 2 + u) * 512);
      }
    }
    #pragma unroll
    for (int u = 0; u < 2; ++u) {
      const int ks = c * 2 + u;
      f16x8 a[2];
      #pragma unroll
      for (int mt = 0; mt < 2; ++mt) {
        int row = mt * 16 + lrow;
        int off = row * SSTRB + (ks * 32 + lk8 * 8) * 2;
        a[mt] = *(const f16x8*)((const char*)srcA + (off ^ ((row & 7) << 4)));
      }
      #pragma unroll
      for (int mt = 0; mt < 2; ++mt)
        #pragma unroll
        for (int nt = 0; nt < 2; ++nt)
          acc[mt][nt] = __builtin_amdgcn_mfma_f32_16x16x32_f16(a[mt], b[cur][u][nt],
                                                               acc[mt][nt], 0, 0, 0);
    }
  }
}

// relu(acc + bias) -> fp16 LDS tile [32][512], swizzled, row stride 1024B.
// Packed pair-stores via shfl_xor -> all-lane ds_write_b32.
__device__ __forceinline__ void epi_relu(const f32x4 (&acc)[2][2],
                                         const float* __restrict__ bias,
                                         f16* dst, int lrow, int lk8, int npanel)
{
  const bool ev = (lrow & 1) == 0;
  #pragma unroll
  for (int nt = 0; nt < 2; ++nt) {
    int n = npanel + nt * 16 + lrow;
    float bv = bias[n];
    #pragma unroll
    for (int j = 0; j < 4; ++j) {
      float v0 = fmaxf(acc[0][nt][j] + bv, 0.f);
      float v1 = fmaxf(acc[1][nt][j] + bv, 0.f);
      float p0 = __shfl_xor(v0, 1);
      float p1 = __shfl_xor(v1, 1);
      float lo = ev ? v0 : p1;
      float hi = ev ? p0 : v1;
      int m = (ev ? 0 : 16) + lk8 * 4 + j;
      int nw = n & ~1;
      unsigned int w = (unsigned int)__builtin_bit_cast(unsigned short, (f16)lo)
                     | ((unsigned int)__builtin_bit_cast(unsigned short, (f16)hi) << 16);
      int off = m * 1024 + nw * 2;
      *(unsigned int*)((char*)dst + (off ^ ((m & 7) << 4))) = w;
    }
  }
}

__global__ __launch_bounds__(1024, 4) void iaf_main(
    const float* __restrict__ mean, const float* __restrict__ logv,
    const float* __restrict__ eps,
    const float* __restrict__ b1, const float* __restrict__ b2,
    const float* __restrict__ b3,
    const f16* __restrict__ ws, float* __restrict__ out)
{
  __shared__ float xbuf[32][XSTR];                // 33.3 KB fp32 master x
  __shared__ __align__(16) f16 buf0[32 * 512];    // 32 KB (A1 uses 16 KB)
  __shared__ __align__(16) f16 buf1[32 * 512];    // 32 KB

  const int tid = threadIdx.x;
  const int wid = tid >> 6;
  const int lane = tid & 63;
  const int lrow = lane & 15;    // MFMA row (A) / col (B,C)
  const int lk8 = lane >> 4;     // MFMA k-chunk / row-group
  const int npanel = wid * 32;   // this wave's 32-column output panel
  const int tbase = wid * 2;     // first 16-col tile index
  const int row0 = blockIdx.x * 32;

  // x0 = mean + exp(0.5*log_var)*eps
  {
    int m = tid >> 5;
    int c0 = (tid & 31) * 8;
    const int g = (row0 + m) * ND + c0;
    #pragma unroll
    for (int i = 0; i < 8; i += 4) {
      f32x4 mu = *(const f32x4*)(mean + g + i);
      f32x4 lv = *(const f32x4*)(logv + g + i);
      f32x4 ep = *(const f32x4*)(eps + g + i);
      f32x4 x;
      #pragma unroll
      for (int q = 0; q < 4; ++q) x[q] = mu[q] + __expf(0.5f * lv[q]) * ep[q];
      *(f32x4*)(&xbuf[m][c0 + i]) = x;
    }
  }
  __syncthreads();

  for (int t = NT - 1; t >= 0; --t) {
    // A1[m][k] = fp16(x[m][255-k]) (reversal folded in), stride 512B, swizzled
    {
      int m = tid >> 5;
      int k0 = (tid & 31) * 8;
      f32x4 lo = *(const f32x4*)(&xbuf[m][248 - k0]);
      f32x4 hi = *(const f32x4*)(&xbuf[m][252 - k0]);
      f16x8 pk;
      pk[0] = (f16)hi[3]; pk[1] = (f16)hi[2]; pk[2] = (f16)hi[1]; pk[3] = (f16)hi[0];
      pk[4] = (f16)lo[3]; pk[5] = (f16)lo[2]; pk[6] = (f16)lo[1]; pk[7] = (f16)lo[0];
      int off = m * 512 + k0 * 2;
      *(f16x8*)((char*)buf0 + (off ^ ((m & 7) << 4))) = pk;
    }
    __syncthreads();

    f32x4 acc[2][2];

    // h1 = relu(x_rev @ W1m + b1)
    gemm_block<ND, 512>(buf0, ws + W1F_OFF + t * (NH * ND), lrow, lk8, lane, tbase, acc);
    epi_relu(acc, b1 + t * NH, buf1, lrow, lk8, npanel);
    __syncthreads();

    // h2 = relu(h1 @ W2m + b2)
    gemm_block<NH, 1024>(buf1, ws + W2F_OFF + t * (NH * NH), lrow, lk8, lane, tbase, acc);
    epi_relu(acc, b2 + t * NH, buf0, lrow, lk8, npanel);
    __syncthreads();

    // out = h2 @ W3m + b3 ;  shift = out[:,2d], log_var = out[:,2d+1]
    gemm_block<NH, 1024>(buf0, ws + W3F_OFF + t * (NH * NH), lrow, lk8, lane, tbase, acc);
    {
      const bool ev = (lrow & 1) == 0;
      float xn0[2][4], xn1[2][4];
      const float* b3t = b3 + t * (2 * ND);
      #pragma unroll
      for (int nt = 0; nt < 2; ++nt) {
        int n = npanel + nt * 16 + lrow;
        float bv = b3t[n];
        #pragma unroll
        for (int j = 0; j < 4; ++j) {
          float o0 = acc[0][nt][j] + bv;
          float o1 = acc[1][nt][j] + bv;
          float po0 = __shfl_xor(o0, 1);   // partner column (n^1) value
          float po1 = __shfl_xor(o1, 1);
          if (ev) {                         // even col: o=shift, po=pre-tanh lv
            int d = n >> 1;
            float xc = xbuf[lk8 * 4 + j][255 - d];
            float e0 = __expf(2.f * po0);
            float t0 = 1.f - 2.f / (e0 + 1.f);          // tanh(po0)
            xn0[nt][j] = (xc - o0) * __expf(-t0);
            float xc1 = xbuf[16 + lk8 * 4 + j][255 - d];
            float e1 = __expf(2.f * po1);
            float t1 = 1.f - 2.f / (e1 + 1.f);
            xn1[nt][j] = (xc1 - o1) * __expf(-t1);
          }
        }
      }
      __syncthreads();                      // all xbuf reads done
      if (ev) {
        #pragma unroll
        for (int nt = 0; nt < 2; ++nt) {
          int d = (npanel + nt * 16 + lrow) >> 1;
          #pragma unroll
          for (int j = 0; j < 4; ++j) {
            xbuf[lk8 * 4 + j][d]      = xn0[nt][j];
            xbuf[16 + lk8 * 4 + j][d] = xn1[nt][j];
          }
        }
      }
      __syncthreads();
    }
  }

  // store final x (fp32)
  {
    int m = tid >> 5;
    int c0 = (tid & 31) * 8;
    float* op = out + (row0 + m) * ND + c0;
    #pragma unroll
    for (int i = 0; i < 8; i += 4)
      *(f32x4*)(op + i) = *(const f32x4*)(&xbuf[m][c0 + i]);
  }
}

extern "C" void kernel_launch(void* const* d_in, const int* in_sizes, int n_in,
                              void* d_out, int out_size, void* d_ws, size_t ws_size,
                              hipStream_t stream) {
  const float* mean = (const float*)d_in[0];
  const float* logv = (const float*)d_in[1];
  const float* eps  = (const float*)d_in[2];
  const float* W1   = (const float*)d_in[3];
  const float* b1   = (const float*)d_in[4];
  const float* W2   = (const float*)d_in[5];
  const float* b2   = (const float*)d_in[6];
  const float* W3   = (const float*)d_in[7];
  const float* b3   = (const float*)d_in[8];
  f16* ws = (f16*)d_ws;   // needs 5.25 MB

  prep_weights<<<(WS_ELEMS + 255) / 256, 256, 0, stream>>>(W1, W2, W3, ws);
  iaf_main<<<NB / 32, 1024, 0, stream>>>(mean, logv, eps, b1, b2, b3, ws,
                                         (float*)d_out);
}